// Round 5
// baseline (476.407 us; speedup 1.0000x reference)
//
#include <hip/hip_runtime.h>
#include <math.h>

// ---------------------------------------------------------------------------
// NFM forward, fused split-fp16 MFMA kernel. R5: async x staging + barrier-free
// K-loops.
//   - 32-row blocks, 256 thr (4 waves), 4096 blocks, 3 blocks/CU (50KB LDS),
//     __launch_bounds__(256,3) -> 170-reg budget, no spill by construction.
//   - x staged ONCE as raw fp32 via global_load_lds (row stride 260 f32,
//     2-way-bank-free frag reads). Split-f16 conversion happens at frag-read
//     time in registers. FM K-loop has ZERO internal barriers.
//   - Activations (tmp/h1/h2) stored as {hi,lo}-interleaved u32 planes,
//     strides 260/132/100 (all ==4 mod 32 -> 2-way alias only).
//   - 7 barriers/block total.
// Stages: FM tmp=0.5*((x@V)^2+(x^2)@(V^2)) [xv split x3 + sq x1];
//   lin=x@w_wide (from LDS x); l1/l2/l3 tower split-f16; sigmoid out.
// MFMA v_mfma_f32_16x16x32_f16, verified layouts:
//   A[m=lane&15][k=(lane>>4)*8+j]; D: col=lane&15, row=(lane>>4)*4+reg.
// ---------------------------------------------------------------------------

typedef _Float16 f16;
typedef _Float16 f16x8 __attribute__((ext_vector_type(8)));
typedef float f32x4 __attribute__((ext_vector_type(4)));
typedef unsigned int u32;
typedef u32 u32x4 __attribute__((ext_vector_type(4)));

#define NROWS   131072
#define ROWS    32
#define FDIM    256
#define KDIM    256
#define D1      128
#define D2      85

// workspace byte offsets (weights only, ~600KB, L2-resident)
#define OFF_VT_H   0x0UL       // [256][256] f16
#define OFF_VT_L   0x20000UL
#define OFF_V2T    0x40000UL
#define OFF_W1T_H  0x60000UL   // [128][256] f16
#define OFF_W1T_L  0x70000UL
#define OFF_W2T_H  0x80000UL   // [128][128] f16 (N padded 85->128)
#define OFF_W2T_L  0x88000UL
#define OFF_W3T_H  0x90000UL   // [64][96] f16 (K padded 85->96)
#define OFF_W3T_L  0x93000UL

static __device__ __forceinline__ f32x4 mfma16(f16x8 a, f16x8 b, f32x4 c) {
  return __builtin_amdgcn_mfma_f32_16x16x32_f16(a, b, c, 0, 0, 0);
}

static __device__ __forceinline__ u32 pack2(float v) {
  f16 hi = (f16)v;
  f16 lo = (f16)(v - (float)hi);
  union { f16 f[2]; u32 u; } t;
  t.f[0] = hi;
  t.f[1] = lo;
  return t.u;
}

static __device__ __forceinline__ void unpack8(u32x4 a, u32x4 b, f16x8* H,
                                               f16x8* L) {
  union { u32 u; f16 f[2]; } t;
  u32 w[8] = {a.x, a.y, a.z, a.w, b.x, b.y, b.z, b.w};
#pragma unroll
  for (int j = 0; j < 8; ++j) {
    t.u = w[j];
    (*H)[j] = t.f[0];
    (*L)[j] = t.f[1];
  }
}

// ---------------------------------------------------------------------------
__global__ __launch_bounds__(256) void prep_kernel(
    const float* __restrict__ V, const float* __restrict__ w1,
    const float* __restrict__ w2, const float* __restrict__ w3,
    f16* VT_h, f16* VT_l, f16* V2T,
    f16* W1T_h, f16* W1T_l, f16* W2T_h, f16* W2T_l, f16* W3T_h, f16* W3T_l) {
  int idx0 = blockIdx.x * 256 + threadIdx.x;
  int stride = gridDim.x * 256;
  for (int idx = idx0; idx < KDIM * FDIM; idx += stride) {
    int k = idx >> 8, i = idx & 255;          // VT[k][i] = V[i][k]
    float v = V[i * KDIM + k];
    f16 h = (f16)v;
    VT_h[idx] = h;
    VT_l[idx] = (f16)(v - (float)h);
    V2T[idx] = (f16)(v * v);
  }
  for (int idx = idx0; idx < D1 * KDIM; idx += stride) {
    int n = idx >> 8, k = idx & 255;          // W1T[n][k] = w1[k][n]
    float w = w1[k * D1 + n];
    f16 h = (f16)w;
    W1T_h[idx] = h;
    W1T_l[idx] = (f16)(w - (float)h);
  }
  for (int idx = idx0; idx < 128 * 128; idx += stride) {
    int n = idx >> 7, k = idx & 127;          // W2T[n][k], n>=85 -> 0
    float w = (n < D2) ? w2[k * D2 + n] : 0.f;
    f16 h = (f16)w;
    W2T_h[idx] = h;
    W2T_l[idx] = (f16)(w - (float)h);
  }
  for (int idx = idx0; idx < 64 * 96; idx += stride) {
    int n = idx / 96, k = idx - n * 96;       // W3T[n][k], k>=85 -> 0
    float w = (k < D2) ? w3[k * 64 + n] : 0.f;
    f16 h = (f16)w;
    W3T_h[idx] = h;
    W3T_l[idx] = (f16)(w - (float)h);
  }
}

// ---------------------------------------------------------------------------
__global__ __launch_bounds__(256, 3) void fused_kernel(
    const float* __restrict__ x, const float* __restrict__ w_wide,
    const float* __restrict__ b_wide,
    const f16* __restrict__ VT_h, const f16* __restrict__ VT_l,
    const f16* __restrict__ V2T,
    const f16* __restrict__ W1T_h, const f16* __restrict__ W1T_l,
    const float* __restrict__ b1,
    const f16* __restrict__ W2T_h, const f16* __restrict__ W2T_l,
    const float* __restrict__ b2,
    const f16* __restrict__ W3T_h, const f16* __restrict__ W3T_l,
    const float* __restrict__ b3,
    const float* __restrict__ w_out, const float* __restrict__ b_out,
    float* __restrict__ out) {
  // Region A (u32[32*260]): raw x (f32) -> tmp {hi,lo} -> h2 {hi,lo}
  // Region B (u32[32*132]): h1 {hi,lo}
  __shared__ __align__(16) u32 arena[32 * 260 + 32 * 132];
  __shared__ float linS[ROWS];
  __shared__ float pfS[ROWS * 4];

  const int tid = threadIdx.x;
  const int lane = tid & 63, wv = tid >> 6;   // wv 0..3
  const int q = lane >> 4, ln = lane & 15;
  const int row0 = blockIdx.x * ROWS;

  // ---- stage x: 8 rows per wave, async global->LDS, stride 260 f32 --------
  {
    const int r = wv * 8;
#pragma unroll
    for (int i = 0; i < 8; ++i) {
      const float* src = x + (size_t)(row0 + r + i) * FDIM + (lane << 2);
      float* dst = (float*)arena + (size_t)(r + i) * 260;
      __builtin_amdgcn_global_load_lds(
          (const __attribute__((address_space(1))) u32*)src,
          (__attribute__((address_space(3))) u32*)dst, 16, 0, 0);
    }
  }
  __syncthreads();  // B1: x resident in LDS

  // ---- wide/linear part from LDS x (xS read-only until B2) ----------------
  {
    int lr = tid >> 3, lj = tid & 7;
    const float* xrow = (const float*)arena + lr * 260 + lj * 4;
    float lp = 0.f;
#pragma unroll
    for (int t = 0; t < 8; ++t) {
      float4 v = *(const float4*)(xrow + t * 32);
      float4 w = *(const float4*)(w_wide + lj * 4 + t * 32);
      lp += v.x * w.x + v.y * w.y + v.z * w.z + v.w * w.w;
    }
    lp += __shfl_xor(lp, 1);
    lp += __shfl_xor(lp, 2);
    lp += __shfl_xor(lp, 4);
    if (lj == 0) linS[lr] = lp + b_wide[0];
  }

  // ---- FM: 2 m-tiles x 4 n-tiles per wave (n-quarter wv), K=256, 0 barriers
  f32x4 accV[2][4], acc2[2][4];
#pragma unroll
  for (int i = 0; i < 2; ++i)
#pragma unroll
    for (int j = 0; j < 4; ++j) {
      accV[i][j] = (f32x4){0.f, 0.f, 0.f, 0.f};
      acc2[i][j] = (f32x4){0.f, 0.f, 0.f, 0.f};
    }
  {
    const float* xS = (const float*)arena;
#pragma unroll 1
    for (int ks = 0; ks < 8; ++ks) {
      const int k0 = ks * 32;
      f16x8 Bh[4], Bl[4], B2[4];
#pragma unroll
      for (int ni = 0; ni < 4; ++ni) {
        int n = wv * 64 + ni * 16 + ln;
        size_t boff = (size_t)n * FDIM + k0 + q * 8;
        Bh[ni] = *(const f16x8*)(VT_h + boff);
        Bl[ni] = *(const f16x8*)(VT_l + boff);
        B2[ni] = *(const f16x8*)(V2T + boff);
      }
#pragma unroll
      for (int mi = 0; mi < 2; ++mi) {
        const float* xp = xS + (mi * 16 + ln) * 260 + k0 + q * 8;
        float4 r0 = *(const float4*)(xp);
        float4 r1 = *(const float4*)(xp + 4);
        float f[8] = {r0.x, r0.y, r0.z, r0.w, r1.x, r1.y, r1.z, r1.w};
        f16x8 Ah, Al, A2;
#pragma unroll
        for (int j = 0; j < 8; ++j) {
          f16 h = (f16)f[j];
          Ah[j] = h;
          Al[j] = (f16)(f[j] - (float)h);
          A2[j] = (f16)(f[j] * f[j]);
        }
#pragma unroll
        for (int ni = 0; ni < 4; ++ni) {
          accV[mi][ni] = mfma16(Al, Bh[ni], accV[mi][ni]);
          accV[mi][ni] = mfma16(Ah, Bl[ni], accV[mi][ni]);
          accV[mi][ni] = mfma16(Ah, Bh[ni], accV[mi][ni]);
          acc2[mi][ni] = mfma16(A2, B2[ni], acc2[mi][ni]);
        }
      }
    }
  }
  __syncthreads();  // B2: all xS reads done, region A reusable

  // ---- FM epilogue: tmp {hi,lo} u32, stride 260, region A -----------------
  {
    u32* tmpS = arena;
#pragma unroll
    for (int mi = 0; mi < 2; ++mi)
#pragma unroll
      for (int r = 0; r < 4; ++r) {
        int m = mi * 16 + q * 4 + r;
        u32* rowp = tmpS + m * 260;
#pragma unroll
        for (int ni = 0; ni < 4; ++ni) {
          int n = wv * 64 + ni * 16 + ln;
          float xv = accV[mi][ni][r];
          rowp[n] = pack2(0.5f * (xv * xv + acc2[mi][ni][r]));
        }
      }
  }
  __syncthreads();  // B3: tmp ready

  // ---- l1: h1 = relu(tmp@w1+b1), N=128, K=256; 2mi x 2nj per wave ---------
  f32x4 acc1[2][2];
#pragma unroll
  for (int i = 0; i < 2; ++i) {
    acc1[i][0] = (f32x4){0.f, 0.f, 0.f, 0.f};
    acc1[i][1] = (f32x4){0.f, 0.f, 0.f, 0.f};
  }
  {
    const u32* tmpS = arena;
#pragma unroll 1
    for (int ks = 0; ks < 8; ++ks) {
      const int k0 = ks * 32;
      f16x8 Bh[2], Bl[2];
#pragma unroll
      for (int nj = 0; nj < 2; ++nj) {
        int n = wv * 32 + nj * 16 + ln;
        size_t boff = (size_t)n * KDIM + k0 + q * 8;
        Bh[nj] = *(const f16x8*)(W1T_h + boff);
        Bl[nj] = *(const f16x8*)(W1T_l + boff);
      }
#pragma unroll
      for (int mi = 0; mi < 2; ++mi) {
        const u32* tp = tmpS + (mi * 16 + ln) * 260 + k0 + q * 8;
        u32x4 p0 = *(const u32x4*)(tp);
        u32x4 p1 = *(const u32x4*)(tp + 4);
        f16x8 Ah, Al;
        unpack8(p0, p1, &Ah, &Al);
#pragma unroll
        for (int nj = 0; nj < 2; ++nj) {
          acc1[mi][nj] = mfma16(Al, Bh[nj], acc1[mi][nj]);
          acc1[mi][nj] = mfma16(Ah, Bl[nj], acc1[mi][nj]);
          acc1[mi][nj] = mfma16(Ah, Bh[nj], acc1[mi][nj]);
        }
      }
    }
  }
  // l1 epilogue -> region B (disjoint from tmp): no barrier needed
  {
    u32* h1S = arena + 32 * 260;
#pragma unroll
    for (int mi = 0; mi < 2; ++mi)
#pragma unroll
      for (int r = 0; r < 4; ++r) {
        int m = mi * 16 + q * 4 + r;
#pragma unroll
        for (int nj = 0; nj < 2; ++nj) {
          int n = wv * 32 + nj * 16 + ln;
          float z = acc1[mi][nj][r] + b1[n];
          h1S[m * 132 + n] = pack2(z > 0.f ? z : 0.f);
        }
      }
  }
  __syncthreads();  // B4: h1 ready

  // ---- l2: h2 = relu(h1@w2+b2), N=128(pad), K=128; 2mi x 2nj per wave -----
  f32x4 accL2[2][2];
#pragma unroll
  for (int i = 0; i < 2; ++i) {
    accL2[i][0] = (f32x4){0.f, 0.f, 0.f, 0.f};
    accL2[i][1] = (f32x4){0.f, 0.f, 0.f, 0.f};
  }
  {
    const u32* h1S = arena + 32 * 260;
#pragma unroll 1
    for (int ks = 0; ks < 4; ++ks) {
      const int k0 = ks * 32;
      f16x8 Bh[2], Bl[2];
#pragma unroll
      for (int nj = 0; nj < 2; ++nj) {
        int n = wv * 32 + nj * 16 + ln;
        size_t boff = (size_t)n * 128 + k0 + q * 8;
        Bh[nj] = *(const f16x8*)(W2T_h + boff);
        Bl[nj] = *(const f16x8*)(W2T_l + boff);
      }
#pragma unroll
      for (int mi = 0; mi < 2; ++mi) {
        const u32* hp = h1S + (mi * 16 + ln) * 132 + k0 + q * 8;
        u32x4 p0 = *(const u32x4*)(hp);
        u32x4 p1 = *(const u32x4*)(hp + 4);
        f16x8 Ah, Al;
        unpack8(p0, p1, &Ah, &Al);
#pragma unroll
        for (int nj = 0; nj < 2; ++nj) {
          accL2[mi][nj] = mfma16(Al, Bh[nj], accL2[mi][nj]);
          accL2[mi][nj] = mfma16(Ah, Bl[nj], accL2[mi][nj]);
          accL2[mi][nj] = mfma16(Ah, Bh[nj], accL2[mi][nj]);
        }
      }
    }
  }
  // l2 epilogue -> h2 in region A (tmp dead; disjoint from h1): no barrier
  {
    u32* h2S = arena;
#pragma unroll
    for (int mi = 0; mi < 2; ++mi)
#pragma unroll
      for (int r = 0; r < 4; ++r) {
        int m = mi * 16 + q * 4 + r;
#pragma unroll
        for (int nj = 0; nj < 2; ++nj) {
          int n = wv * 32 + nj * 16 + ln;
          if (n < 96) {
            float z = accL2[mi][nj][r] + ((n < D2) ? b2[n] : 0.f);
            h2S[m * 100 + n] = pack2(z > 0.f ? z : 0.f);
          }
        }
      }
  }
  __syncthreads();  // B5: h2 ready

  // ---- l3: K=96, N=64; 2mi x 1 n-tile per wave + final dot ----------------
  f32x4 acc3[2];
  acc3[0] = (f32x4){0.f, 0.f, 0.f, 0.f};
  acc3[1] = (f32x4){0.f, 0.f, 0.f, 0.f};
  {
    const u32* h2S = arena;
    const int n3 = wv * 16 + ln;
#pragma unroll
    for (int ks = 0; ks < 3; ++ks) {
      const int k0 = ks * 32;
      size_t boff = (size_t)n3 * 96 + k0 + q * 8;
      f16x8 Bh = *(const f16x8*)(W3T_h + boff);
      f16x8 Bl = *(const f16x8*)(W3T_l + boff);
#pragma unroll
      for (int mi = 0; mi < 2; ++mi) {
        const u32* hp = h2S + (mi * 16 + ln) * 100 + k0 + q * 8;
        u32x4 p0 = *(const u32x4*)(hp);
        u32x4 p1 = *(const u32x4*)(hp + 4);
        f16x8 Ah, Al;
        unpack8(p0, p1, &Ah, &Al);
        acc3[mi] = mfma16(Al, Bh, acc3[mi]);
        acc3[mi] = mfma16(Ah, Bl, acc3[mi]);
        acc3[mi] = mfma16(Ah, Bh, acc3[mi]);
      }
    }
  }
  {
    const int n3 = wv * 16 + ln;
    float b3v = b3[n3], wov = w_out[n3];
#pragma unroll
    for (int mi = 0; mi < 2; ++mi)
#pragma unroll
      for (int r = 0; r < 4; ++r) {
        float z = acc3[mi][r] + b3v;
        float part = (z > 0.f ? z : 0.f) * wov;
        part += __shfl_xor(part, 1);
        part += __shfl_xor(part, 2);
        part += __shfl_xor(part, 4);
        part += __shfl_xor(part, 8);
        if (ln == 0) pfS[(mi * 16 + q * 4 + r) * 4 + wv] = part;
      }
  }
  __syncthreads();  // B6: partials ready

  if (tid < ROWS) {
    float zf = linS[tid] + pfS[tid * 4] + pfS[tid * 4 + 1] + pfS[tid * 4 + 2] +
               pfS[tid * 4 + 3] + b_out[0];
    out[row0 + tid] = 1.f / (1.f + expf(-zf));
  }
}

// ---------------------------------------------------------------------------
extern "C" void kernel_launch(void* const* d_in, const int* in_sizes, int n_in,
                              void* d_out, int out_size, void* d_ws, size_t ws_size,
                              hipStream_t stream) {
  const float* x = (const float*)d_in[0];
  const float* w_wide = (const float*)d_in[1];
  const float* b_wide = (const float*)d_in[2];
  const float* V = (const float*)d_in[3];
  const float* w1 = (const float*)d_in[4];
  const float* b1 = (const float*)d_in[5];
  const float* w2 = (const float*)d_in[6];
  const float* b2 = (const float*)d_in[7];
  const float* w3 = (const float*)d_in[8];
  const float* b3 = (const float*)d_in[9];
  const float* w_out = (const float*)d_in[10];
  const float* b_out = (const float*)d_in[11];
  float* out = (float*)d_out;
  char* ws = (char*)d_ws;

  f16* VT_h = (f16*)(ws + OFF_VT_H);
  f16* VT_l = (f16*)(ws + OFF_VT_L);
  f16* V2T = (f16*)(ws + OFF_V2T);
  f16* W1T_h = (f16*)(ws + OFF_W1T_H);
  f16* W1T_l = (f16*)(ws + OFF_W1T_L);
  f16* W2T_h = (f16*)(ws + OFF_W2T_H);
  f16* W2T_l = (f16*)(ws + OFF_W2T_L);
  f16* W3T_h = (f16*)(ws + OFF_W3T_H);
  f16* W3T_l = (f16*)(ws + OFF_W3T_L);

  prep_kernel<<<64, 256, 0, stream>>>(V, w1, w2, w3, VT_h, VT_l, V2T, W1T_h,
                                      W1T_l, W2T_h, W2T_l, W3T_h, W3T_l);

  fused_kernel<<<NROWS / ROWS, 256, 0, stream>>>(
      x, w_wide, b_wide, VT_h, VT_l, V2T, W1T_h, W1T_l, b1, W2T_h, W2T_l, b2,
      W3T_h, W3T_l, b3, w_out, b_out, out);
}